// Round 4
// baseline (3685.666 us; speedup 1.0000x reference)
//
#include <hip/hip_runtime.h>
#include <stdint.h>
#include <stddef.h>

#define B_  2
#define S_  2048
#define E_  4096
#define H_  16
#define D_  256
#define INNER_ 16384
#define M_  (B_*S_)

typedef __attribute__((ext_vector_type(4))) float f32x4;
// bf16 MFMA fragment: raw-bits short vector, matching the environment's
// compile-verified example (examples/mfma_bf16_gemm_tile.cpp). If the local
// builtin signature wants __bf16 vectors instead, flip this typedef.
typedef __attribute__((ext_vector_type(8))) short bf16x8;
typedef __attribute__((ext_vector_type(4))) unsigned short u16x4;
typedef __attribute__((ext_vector_type(8))) unsigned short u16x8;

typedef __attribute__((address_space(1))) void* as1p;
typedef __attribute__((address_space(3))) void* as3p;

__device__ __forceinline__ unsigned short f2bf(float f){
  union { float f; unsigned u; } v; v.f = f;
  unsigned u = v.u + 0x7fffu + ((v.u >> 16) & 1u);
  return (unsigned short)(u >> 16);
}
__device__ __forceinline__ float bf2f(unsigned short s){
  union { unsigned u; float f; } v; v.u = ((unsigned)s) << 16; return v.f;
}
__device__ __forceinline__ void gload16(const void* g, void* l){
  __builtin_amdgcn_global_load_lds((as1p)(g), (as3p)(l), 16, 0, 0);
}
__device__ __forceinline__ f32x4 mfma16x16x32(bf16x8 a, bf16x8 b, f32x4 c){
  return __builtin_amdgcn_mfma_f32_16x16x32_bf16(a, b, c, 0, 0, 0);
}

// ---------------- LayerNorm: fp32 in -> bf16 h ----------------
__global__ __launch_bounds__(256) void ln_kernel(const float* __restrict__ x,
    const float* __restrict__ gg, const float* __restrict__ bb,
    unsigned short* __restrict__ h){
  int row = blockIdx.x;
  const float* xr = x + (size_t)row * E_;
  int t = threadIdx.x;
  f32x4 v[4];
  float s = 0.f, ss = 0.f;
#pragma unroll
  for (int i=0;i<4;i++){
    v[i] = *(const f32x4*)(xr + (t + i*256)*4);
#pragma unroll
    for (int j=0;j<4;j++){ s += v[i][j]; ss += v[i][j]*v[i][j]; }
  }
#pragma unroll
  for (int off=32; off; off>>=1){ s += __shfl_xor(s, off); ss += __shfl_xor(ss, off); }
  __shared__ float red[8];
  int w = t>>6, l = t&63;
  if (l==0){ red[w]=s; red[4+w]=ss; }
  __syncthreads();
  s  = red[0]+red[1]+red[2]+red[3];
  ss = red[4]+red[5]+red[6]+red[7];
  float mu = s * (1.f/E_);
  float var = ss * (1.f/E_) - mu*mu;
  float rs = rsqrtf(var + 1e-5f);
  unsigned short* hr = h + (size_t)row*E_;
#pragma unroll
  for (int i=0;i<4;i++){
    int idx = (t + i*256)*4;
    f32x4 gv = *(const f32x4*)(gg + idx);
    f32x4 bv = *(const f32x4*)(bb + idx);
    u16x4 o;
#pragma unroll
    for (int j=0;j<4;j++) o[j] = f2bf((v[i][j]-mu)*rs*gv[j] + bv[j]);
    *(u16x4*)(hr + idx) = o;
  }
}

// ------- transpose + fp32->bf16: src [R][C] -> dst [C][R] -------
__global__ __launch_bounds__(256) void transpose_cvt(const float* __restrict__ src,
    unsigned short* __restrict__ dst, int R, int C){
  int rtiles = R >> 6;
  int rt = blockIdx.x % rtiles, ct = blockIdx.x / rtiles;
  int r0 = rt<<6, c0 = ct<<6;
  __shared__ float tile[64][65];
  int t = threadIdx.x;
#pragma unroll
  for (int p=0;p<4;p++){
    int idx = t + p*256;
    int row = idx >> 4, col4 = (idx & 15) << 2;
    f32x4 v = *(const f32x4*)(src + (size_t)(r0+row)*C + c0 + col4);
#pragma unroll
    for (int j=0;j<4;j++) tile[row][col4+j] = v[j];
  }
  __syncthreads();
#pragma unroll
  for (int p=0;p<2;p++){
    int idx = t + p*256;
    int cr = idx >> 3, ch = (idx & 7) << 3;
    u16x8 o;
#pragma unroll
    for (int j=0;j<8;j++) o[j] = f2bf(tile[ch+j][cr]);
    *(u16x8*)(dst + (size_t)(c0+cr)*R + r0 + ch) = o;
  }
}

// ---- past cache (B,T,H,D) fp32 -> (B,H,T,D) bf16 ----
__global__ __launch_bounds__(256) void cache_init(const float* __restrict__ past,
    unsigned short* __restrict__ cache){
  size_t e = ((size_t)blockIdx.x * 256 + threadIdx.x) * 4;
  int d  = (int)(e & (D_-1));
  int hh = (int)((e >> 8) & (H_-1));
  int tt = (int)((e >> 12) & (S_-1));
  int bb2 = (int)(e >> 23);
  f32x4 v = *(const f32x4*)(past + e);
  u16x4 o = { f2bf(v[0]), f2bf(v[1]), f2bf(v[2]), f2bf(v[3]) };
  *(u16x4*)(cache + (((size_t)(bb2*H_ + hh)*S_ + tt)*D_ + d)) = o;
}

// ---------------- GEMM: C[M,N] = A[M,K] * BT[N,K]^T ----------------
// EPI 0: store bf16
// EPI 1: bf16( gelu(acc + bias[n]) )      via x*sigmoid(2y), overflow-safe
// EPI 2: f32( acc + bias[n] + add[m,n] )
// EPI 3: f32( acc + add[m,n] )     (add == out allowed)
template<int EPI>
__global__ __launch_bounds__(256) void gemm_bf16(const unsigned short* __restrict__ A,
    const unsigned short* __restrict__ BT, void* __restrict__ outp,
    const float* __restrict__ bias, const float* __restrict__ add,
    int M, int N, int K){
  int rowTiles = M >> 7;
  int rt = blockIdx.x % rowTiles, ctile = blockIdx.x / rowTiles;
  int m0 = rt << 7, n0 = ctile << 7;
  __shared__ unsigned short lA[128*32];
  __shared__ unsigned short lB[128*32];
  int t = threadIdx.x, w = t >> 6, l = t & 63;
  int wm = (w >> 1) << 6, wn = (w & 1) << 6;
  int r = l & 15, g8 = (l >> 4) << 3;
  f32x4 acc[4][4] = {};
  const unsigned short* Aa = A + (size_t)(m0 + (w<<4) + (l>>2))*K + ((l&3)<<3);
  const unsigned short* Bb = BT + (size_t)(n0 + (w<<4) + (l>>2))*K + ((l&3)<<3);
  const size_t step64 = (size_t)64 * K;
  for (int k0 = 0; k0 < K; k0 += 32){
    __syncthreads();
    gload16(Aa + k0,          lA + ((size_t)w<<9));
    gload16(Aa + k0 + step64, lA + ((size_t)(w+4)<<9));
    gload16(Bb + k0,          lB + ((size_t)w<<9));
    gload16(Bb + k0 + step64, lB + ((size_t)(w+4)<<9));
    __syncthreads();
    bf16x8 af[4], bfr[4];
#pragma unroll
    for (int mi=0;mi<4;mi++) af[mi]  = *(const bf16x8*)(lA + (wm + mi*16 + r)*32 + g8);
#pragma unroll
    for (int nj=0;nj<4;nj++) bfr[nj] = *(const bf16x8*)(lB + (wn + nj*16 + r)*32 + g8);
#pragma unroll
    for (int mi=0;mi<4;mi++)
#pragma unroll
      for (int nj=0;nj<4;nj++)
        acc[mi][nj] = mfma16x16x32(af[mi], bfr[nj], acc[mi][nj]);
  }
  int gq = l >> 4;
#pragma unroll
  for (int nj=0;nj<4;nj++){
    int col = n0 + wn + nj*16 + r;
    float bcol = (EPI==1 || EPI==2) ? bias[col] : 0.f;
#pragma unroll
    for (int mi=0;mi<4;mi++){
#pragma unroll
      for (int i=0;i<4;i++){
        int row = m0 + wm + mi*16 + gq*4 + i;
        float vv = acc[mi][nj][i];
        size_t oidx = (size_t)row*N + col;
        if (EPI==0){
          ((unsigned short*)outp)[oidx] = f2bf(vv);
        } else if (EPI==1){
          float xg = vv + bcol;
          // gelu_tanh(x) = 0.5x(1+tanh(y)) = x * sigmoid(2y), y = 0.79788456(x+0.044715x^3)
          float sg = 1.f / (1.f + __expf(-1.5957691216057308f*(xg + 0.044715f*xg*xg*xg)));
          ((unsigned short*)outp)[oidx] = f2bf(xg * sg);
        } else if (EPI==2){
          ((float*)outp)[oidx] = vv + bcol + add[oidx];
        } else {
          ((float*)outp)[oidx] = vv + add[oidx];
        }
      }
    }
  }
}

// ------- RoPE + scatter into caches; qkv [B*S][3E] bf16 -------
__global__ __launch_bounds__(256) void rope_scatter_kernel(
    const unsigned short* __restrict__ qkv, const int* __restrict__ pos,
    const int* __restrict__ kloc, const int* __restrict__ vloc,
    unsigned short* __restrict__ qr, unsigned short* __restrict__ kc,
    unsigned short* __restrict__ vc){
  int bs = blockIdx.x;
  int b = bs >> 11, s = bs & (S_-1);
  int t = threadIdx.x;
  int h = t >> 4, d0 = (t & 15) << 4;
  float pf = (float)pos[bs];
  int kl = kloc[bs], vl = vloc[bs];
  const unsigned short* base = qkv + (size_t)bs*(3*E_) + h*D_ + d0;
  u16x8 q0 = *(const u16x8*)(base);
  u16x8 q1 = *(const u16x8*)(base + 8);
  u16x8 k0 = *(const u16x8*)(base + E_);
  u16x8 k1 = *(const u16x8*)(base + E_ + 8);
  u16x8 v0 = *(const u16x8*)(base + 2*E_);
  u16x8 v1 = *(const u16x8*)(base + 2*E_ + 8);
  if (d0 < 64){
    float qa[16], ka[16];
#pragma unroll
    for (int e=0;e<8;e++){ qa[e]=bf2f(q0[e]); qa[8+e]=bf2f(q1[e]);
                           ka[e]=bf2f(k0[e]); ka[8+e]=bf2f(k1[e]); }
#pragma unroll
    for (int u=0;u<8;u++){
      int j = (d0>>1) + u;
      float inv = powf(10000.f, -(float)(2*j) * (1.f/64.f));
      float sn, cs; sincosf(pf*inv, &sn, &cs);
      float xe=qa[2*u], xo=qa[2*u+1];
      qa[2*u]   = xe*cs - xo*sn;
      qa[2*u+1] = xo*cs + xe*sn;
      xe=ka[2*u]; xo=ka[2*u+1];
      ka[2*u]   = xe*cs - xo*sn;
      ka[2*u+1] = xo*cs + xe*sn;
    }
#pragma unroll
    for (int e=0;e<8;e++){ q0[e]=f2bf(qa[e]); q1[e]=f2bf(qa[8+e]);
                           k0[e]=f2bf(ka[e]); k1[e]=f2bf(ka[8+e]); }
  }
  size_t orow = (size_t)(b*H_ + h)*S_;
  unsigned short* qd = qr + (orow + s)*D_ + d0;
  *(u16x8*)qd = q0; *(u16x8*)(qd+8) = q1;
  unsigned short* kd = kc + (orow + kl)*D_ + d0;
  *(u16x8*)kd = k0; *(u16x8*)(kd+8) = k1;
  unsigned short* vd = vc + (orow + vl)*D_ + d0;
  *(u16x8*)vd = v0; *(u16x8*)(vd+8) = v1;
}

// ---------------- Flash attention, causal, 4 waves x 16 q-rows ----------------
__global__ __launch_bounds__(256) void attn_kernel(const unsigned short* __restrict__ qr,
    const unsigned short* __restrict__ kc, const unsigned short* __restrict__ vc,
    unsigned short* __restrict__ ctx){
  int bh = blockIdx.x >> 5, qt = blockIdx.x & 31;
  int qb = qt << 6;
  int t = threadIdx.x, w = t >> 6, l = t & 63;
  int r = l & 15, g = l >> 4;
  int qlo = qb + (w << 4);
  size_t bhbase = (size_t)bh * (S_ * D_);
  __shared__ unsigned short Kl[32*256];   // row-swizzled (byte ^= (row&7)<<4)
  __shared__ unsigned short Vt[256*40];   // transposed [d][k], pad 40
  bf16x8 qf[8];
  const unsigned short* qrow = qr + bhbase + (size_t)(qlo + r)*D_ + g*8;
#pragma unroll
  for (int ds=0; ds<8; ds++) qf[ds] = *(const bf16x8*)(qrow + ds*32);
  f32x4 o[16] = {};
  float mrow = -1e30f, lrow = 0.f;
  int nkv = (qb >> 5) + 2;
  int vk = t & 31;
  int vdb = (t >> 5) << 5;
  for (int kt = 0; kt < nkv; kt++){
    int kv0 = kt << 5;
    __syncthreads();
#pragma unroll
    for (int ci=0; ci<4; ci++){
      int c = (w<<2) + ci;
      int krow = (c<<1) + (l>>5);
      int offb = (l&31) << 4;
      int srcb = offb ^ ((krow & 7) << 4);   // pre-swizzled source, linear LDS dest
      gload16(kc + bhbase + (size_t)(kv0 + krow)*D_ + (srcb>>1), Kl + (size_t)c*512);
    }
    {
      const unsigned short* vrow = vc + bhbase + (size_t)(kv0 + vk)*D_ + vdb;
      u16x8 vv[4];
#pragma unroll
      for (int i=0;i<4;i++) vv[i] = *(const u16x8*)(vrow + i*8);
#pragma unroll
      for (int i=0;i<4;i++)
#pragma unroll
        for (int j=0;j<8;j++) Vt[(vdb + i*8 + j)*40 + vk] = vv[i][j];
    }
    __syncthreads();
    if (kv0 <= qlo + 15){
      f32x4 c0 = {0.f,0.f,0.f,0.f}, c1 = {0.f,0.f,0.f,0.f};
#pragma unroll
      for (int ds=0; ds<8; ds++){
        int off = ((ds<<6) + (g<<4)) ^ ((r & 7) << 4);
        bf16x8 a0 = *(const bf16x8*)((const char*)Kl + (r<<9) + off);
        bf16x8 a1 = *(const bf16x8*)((const char*)Kl + ((r+16)<<9) + off);
        c0 = mfma16x16x32(a0, qf[ds], c0);   // S^T[k,q]
        c1 = mfma16x16x32(a1, qf[ds], c1);
      }
      int qg = qlo + r;
      float s8[8];
#pragma unroll
      for (int i=0;i<4;i++){
        int k0i = kv0 + (g<<2) + i;
        s8[i]   = (k0i      <= qg) ? c0[i]*0.0625f : -1e30f;
        s8[4+i] = (k0i + 16 <= qg) ? c1[i]*0.0625f : -1e30f;
      }
      float pm = s8[0];
#pragma unroll
      for (int i=1;i<8;i++) pm = fmaxf(pm, s8[i]);
      pm = fmaxf(pm, __shfl_xor(pm, 16));
      pm = fmaxf(pm, __shfl_xor(pm, 32));
      float mnew = fmaxf(mrow, pm);
      float corr = __expf(mrow - mnew);
      float ps[8]; float psum = 0.f;
#pragma unroll
      for (int i=0;i<8;i++){ ps[i] = __expf(s8[i] - mnew); psum += ps[i]; }
      psum += __shfl_xor(psum, 16);
      psum += __shfl_xor(psum, 32);
      lrow = lrow*corr + psum;
      mrow = mnew;
      // o[nt][i] holds q-row (qlo + g*4 + i); corr lives on lane with r == g*4+i.
      // Remap per C/D row before rescaling (same pattern as linv below).
      float co[4];
#pragma unroll
      for (int i=0;i<4;i++) co[i] = __shfl(corr, (g<<2) + i);
#pragma unroll
      for (int nt=0;nt<16;nt++){
        o[nt][0] *= co[0]; o[nt][1] *= co[1];
        o[nt][2] *= co[2]; o[nt][3] *= co[3];
      }
      unsigned pw[4];
#pragma unroll
      for (int i=0;i<4;i++) pw[i] = (unsigned)f2bf(ps[2*i]) | ((unsigned)f2bf(ps[2*i+1]) << 16);
      // redistribute P (C-layout of S^T) into A-fragment layout for PV
      unsigned aw[4];
#pragma unroll
      for (int wd=0; wd<4; wd++){
        int srcl = r + ((((g & 1) << 1) + (wd >> 1)) << 4);
        unsigned lo2 = __shfl(pw[wd & 1], srcl);
        unsigned hi2 = __shfl(pw[2 + (wd & 1)], srcl);
        aw[wd] = (g < 2) ? lo2 : hi2;
      }
      union { unsigned u[4]; bf16x8 v; } afu;
      afu.u[0]=aw[0]; afu.u[1]=aw[1]; afu.u[2]=aw[2]; afu.u[3]=aw[3];
#pragma unroll
      for (int nt=0;nt<16;nt++){
        bf16x8 bv = *(const bf16x8*)((const char*)Vt + ((nt<<4) + r)*80 + (g<<4));
        o[nt] = mfma16x16x32(afu.v, bv, o[nt]);
      }
    }
  }
  int b = bh >> 4, hh = bh & 15;
  float linv[4];
#pragma unroll
  for (int i=0;i<4;i++) linv[i] = 1.f / __shfl(lrow, (g<<2) + i);
#pragma unroll
  for (int nt=0;nt<16;nt++){
#pragma unroll
    for (int i=0;i<4;i++){
      int sq = qlo + (g<<2) + i;
      ctx[((size_t)(b*S_ + sq))*E_ + hh*D_ + (nt<<4) + r] = f2bf(o[nt][i] * linv[i]);
    }
  }
}

extern "C" void kernel_launch(void* const* d_in, const int* in_sizes, int n_in,
                              void* d_out, int out_size, void* d_ws, size_t ws_size,
                              hipStream_t stream){
  const float* hs   = (const float*)d_in[0];
  const float* lng  = (const float*)d_in[1];
  const float* lnb  = (const float*)d_in[2];
  const float* wq   = (const float*)d_in[3];
  const float* wk   = (const float*)d_in[4];
  const float* wv   = (const float*)d_in[5];
  const float* wo   = (const float*)d_in[6];
  const float* fiw  = (const float*)d_in[7];
  const float* fib  = (const float*)d_in[8];
  const float* fow  = (const float*)d_in[9];
  const float* fob  = (const float*)d_in[10];
  const float* pk   = (const float*)d_in[11];
  const float* pv   = (const float*)d_in[12];
  const int*   kloc = (const int*)d_in[13];
  const int*   vloc = (const int*)d_in[14];
  const int*   pos  = (const int*)d_in[15];
  float* out = (float*)d_out;

  char* p = (char*)d_ws;
  unsigned short* bufA = (unsigned short*)p; p += (size_t)134217728; // qkvT[12288][4096], later fcoutT[4096][16384]
  unsigned short* woT  = (unsigned short*)p; p += (size_t)33554432;  // [4096][4096]
  unsigned short* fiT  = (unsigned short*)p; p += (size_t)134217728; // [16384][4096]
  unsigned short* hbf  = (unsigned short*)p; p += (size_t)33554432;  // [4096][4096]
  unsigned short* qkv  = (unsigned short*)p;                         // [4096][12288] (96MB)
  unsigned short* ffb  = (unsigned short*)p;                         // [4096][16384] aliases qkv+qrb (dead by then)
  unsigned short* qrb  = (unsigned short*)(p + (size_t)100663296);   // (B,H,S,D) 32MB
  p += (size_t)134217728;                                            // union region: max(qkv+qrb, ffb)
  unsigned short* kcb  = (unsigned short*)p; p += (size_t)33554432;  // (B,H,T,D)
  unsigned short* vcb  = (unsigned short*)p; p += (size_t)33554432;  // (B,H,T,D)
  unsigned short* ctx  = (unsigned short*)p; p += (size_t)33554432;  // [4096][4096]

  transpose_cvt<<<4096, 256, 0, stream>>>(wq, bufA, E_, E_);
  transpose_cvt<<<4096, 256, 0, stream>>>(wk, bufA + (size_t)E_*E_,   E_, E_);
  transpose_cvt<<<4096, 256, 0, stream>>>(wv, bufA + (size_t)2*E_*E_, E_, E_);
  transpose_cvt<<<4096, 256, 0, stream>>>(wo, woT, E_, E_);
  transpose_cvt<<<16384, 256, 0, stream>>>(fiw, fiT, E_, INNER_);
  ln_kernel<<<M_, 256, 0, stream>>>(hs, lng, lnb, hbf);
  cache_init<<<16384, 256, 0, stream>>>(pk, kcb);
  cache_init<<<16384, 256, 0, stream>>>(pv, vcb);
  gemm_bf16<0><<<3072, 256, 0, stream>>>(hbf, bufA, qkv, nullptr, nullptr, M_, 3*E_, E_);
  rope_scatter_kernel<<<M_, 256, 0, stream>>>(qkv, pos, kloc, vloc, qrb, kcb, vcb);
  transpose_cvt<<<16384, 256, 0, stream>>>(fow, bufA, INNER_, E_);   // fcoutT into bufA (qkvT dead)
  attn_kernel<<<1024, 256, 0, stream>>>(qrb, kcb, vcb, ctx);         // reads qrb/kcb/vcb
  gemm_bf16<1><<<4096, 256, 0, stream>>>(hbf, fiT, ffb, fib, nullptr, M_, INNER_, E_);  // ffb overwrites qkv/qrb (dead)
  gemm_bf16<2><<<1024, 256, 0, stream>>>(ffb, bufA, out, fob, hs, M_, E_, INNER_);
  gemm_bf16<3><<<1024, 256, 0, stream>>>(ctx, woT, out, nullptr, out, M_, E_, E_);
}